// Round 1
// baseline (323.161 us; speedup 1.0000x reference)
//
#include <hip/hip_runtime.h>
#include <hip/hip_bf16.h>

// PLRNN step: out = A*z + relu(z - rowmean(z)) @ W^T + h,  A=diag(AW), W=AW-diag
// Rewritten: out = (z_act @ AW^T) + [A*min(z,mu) + h]   (exact identity)
// Round 4: BM 32->64 at 512 threads (wave tile 64x64 -> 16 MFMA per 4 B-loads,
// halves B L2 traffic to 512 MB). sC dropped: corr recomputed in the epilogue
// from an L3-hot z re-read + sMu[64]; out stores non-temporal to protect z's
// L3 residency. A-frags single-buffered; B double-buffered; VGPR capped 128
// so 2 blocks/CU stay resident (LDS 66.8 KB/block).

#define DZV 512
#define BM 64
#define LDA 520   // LDS row stride (shorts): 1040 B, 16B-aligned, 2-way-free banks

typedef __attribute__((ext_vector_type(8))) short short8;  // 8 bf16 = 4 VGPRs
typedef __attribute__((ext_vector_type(4))) float f32x4;   // MFMA C/D frag

__device__ __forceinline__ unsigned short f2bf(float x) {
  __hip_bfloat16 b = __float2bfloat16(x);
  return __builtin_bit_cast(unsigned short, b);
}

// Prep: pack AW (fp32) into bf16 MFMA-B-fragment order + extract diagonal.
// Frag idx=(T*16+s)*64+L holds 8 bf16 = AW[T*16+(L&15)][s*32+(L>>4)*8 + j]:
// a wave's B-frag load (lane L reads idx base+L) is 1KB contiguous, L2-hot.
__global__ void pack_b(const float* __restrict__ AW, unsigned short* __restrict__ AWp,
                       float* __restrict__ Adiag) {
  int idx = blockIdx.x * 256 + threadIdx.x;     // 0..32767
  int L = idx & 63, s = (idx >> 6) & 15, T = idx >> 10;
  int n = T * 16 + (L & 15);
  int k = s * 32 + (L >> 4) * 8;
  const float4* src = (const float4*)(AW + n * DZV + k);
  float4 a = src[0], b = src[1];
  union { unsigned short u[8]; short8 v; } p;
  p.u[0] = f2bf(a.x); p.u[1] = f2bf(a.y); p.u[2] = f2bf(a.z); p.u[3] = f2bf(a.w);
  p.u[4] = f2bf(b.x); p.u[5] = f2bf(b.y); p.u[6] = f2bf(b.z); p.u[7] = f2bf(b.w);
  *(short8*)(AWp + idx * 8) = p.v;
  if (idx < DZV) Adiag[idx] = AW[idx * (DZV + 1)];
}

__global__ __launch_bounds__(512, 4) void plrnn_step(
    const float* __restrict__ z, const float* __restrict__ h,
    const unsigned short* __restrict__ AWp, const float* __restrict__ Adiag,
    float* __restrict__ out)
{
  __shared__ unsigned short sA[BM * LDA];  // z_act panel (bf16), 66.6 KB
  __shared__ float sMu[BM];                // per-row mean, 256 B

  const int t = threadIdx.x;
  const int row0 = blockIdx.x * BM;

  const int lane = t & 63;
  const int wave = t >> 6;           // 8 waves cover N=512
  const int lr   = lane & 15;
  const int quad = lane >> 4;
  const int nbase = wave * 64;

  // B frag base pointers (packed global, lane-contiguous 1KB per frag-load)
  const unsigned short* bb[4];
  #pragma unroll
  for (int nt = 0; nt < 4; ++nt)
    bb[nt] = AWp + (((wave * 4 + nt) * 16) * 64 + lane) * 8;

  // ---- Phase 1: two coalesced passes over z (32 rows each); mean -> sMu,
  //      relu(z-mu) -> sA. No corr array: recomputed in epilogue. ----
  {
    const int rr = t >> 4;         // 0..31, 16 threads per row (consecutive lanes)
    const int c = t & 15;
    #pragma unroll
    for (int p = 0; p < 2; ++p) {
      const int r = p * 32 + rr;
      const float4* zr = (const float4*)(z + (row0 + r) * DZV);
      float4 v[8];
      float s = 0.f;
      #pragma unroll
      for (int i = 0; i < 8; ++i) {
        v[i] = zr[c + i * 16];                   // coalesced 256B runs
        s += (v[i].x + v[i].y) + (v[i].z + v[i].w);
      }
      s += __shfl_xor(s, 1);
      s += __shfl_xor(s, 2);
      s += __shfl_xor(s, 4);
      s += __shfl_xor(s, 8);
      const float mu = s * (1.0f / 512.0f);
      if (c == 0) sMu[r] = mu;
      #pragma unroll
      for (int i = 0; i < 8; ++i) {
        const int c4 = c + i * 16;               // float4 column index
        union { unsigned short u[4]; ushort4 v4; } pa;
        pa.u[0] = f2bf(fmaxf(v[i].x - mu, 0.f));
        pa.u[1] = f2bf(fmaxf(v[i].y - mu, 0.f));
        pa.u[2] = f2bf(fmaxf(v[i].z - mu, 0.f));
        pa.u[3] = f2bf(fmaxf(v[i].w - mu, 0.f));
        *(ushort4*)&sA[r * LDA + c4 * 4] = pa.v4;
      }
    }
  }

  // Pre-barrier B prefetch for s=0: loads fly during the barrier drain.
  short8 bf[2][4];
  #pragma unroll
  for (int nt = 0; nt < 4; ++nt)
    bf[0][nt] = *(const short8*)(bb[nt]);

  __syncthreads();   // only barrier; K-loop below is barrier-free

  // ---- Phase 2: GEMM, 4M x 4N frags per wave (64x64 tile).
  //      B double-buffered (L2 latency); A single-buffered (LDS latency,
  //      hidden by 4 waves/SIMD + previous iter's MFMA drain). ----
  const unsigned short* abase = &sA[lr * LDA + quad * 8];

  f32x4 acc[4][4];
  #pragma unroll
  for (int mt = 0; mt < 4; ++mt)
    #pragma unroll
    for (int nt = 0; nt < 4; ++nt)
      acc[mt][nt] = (f32x4){0.f, 0.f, 0.f, 0.f};

  short8 af[4];
  #pragma unroll
  for (int s = 0; s < 16; ++s) {     // k = s*32
    const int cur = s & 1, nxt = cur ^ 1;
    #pragma unroll
    for (int mt = 0; mt < 4; ++mt)   // A frags for THIS step (ds_read_b128)
      af[mt] = *(const short8*)(abase + mt * 16 * LDA + s * 32);
    if (s < 15) {                    // prefetch B for s+1 (L2, dwordx4)
      #pragma unroll
      for (int nt = 0; nt < 4; ++nt)
        bf[nxt][nt] = *(const short8*)(bb[nt] + (s + 1) * 512);
    }
    #pragma unroll
    for (int nt = 0; nt < 4; ++nt)
      #pragma unroll
      for (int mt = 0; mt < 4; ++mt)
        acc[mt][nt] = __builtin_amdgcn_mfma_f32_16x16x32_bf16(af[mt], bf[cur][nt], acc[mt][nt], 0, 0, 0);
  }

  // ---- Epilogue: corr = A*min(z,mu)+h recomputed from z (L3-hot re-read).
  //      nt innermost -> 4 adjacent 64B segments per row; non-temporal out
  //      stores so 134MB of writes don't evict z from L3. ----
  float Ad[4], hv[4];
  #pragma unroll
  for (int nt = 0; nt < 4; ++nt) {
    const int col = nbase + nt * 16 + lr;
    Ad[nt] = Adiag[col];             // L1-hot, 2KB shared
    hv[nt] = h[col];
  }
  #pragma unroll
  for (int mt = 0; mt < 4; ++mt) {
    #pragma unroll
    for (int r = 0; r < 4; ++r) {
      const int lm = mt * 16 + quad * 4 + r;   // C/D layout: row = quad*4 + reg
      const float mu = sMu[lm];                // LDS broadcast (uniform per quad)
      const float* zrow = z + (row0 + lm) * DZV + nbase + lr;
      float* orow = out + (row0 + lm) * DZV + nbase + lr;
      #pragma unroll
      for (int nt = 0; nt < 4; ++nt) {
        const float zv = zrow[nt * 16];
        const float corr = Ad[nt] * fminf(zv, mu) + hv[nt];
        __builtin_nontemporal_store(acc[mt][nt][r] + corr, &orow[nt * 16]);
      }
    }
  }
}

extern "C" void kernel_launch(void* const* d_in, const int* in_sizes, int n_in,
                              void* d_out, int out_size, void* d_ws, size_t ws_size,
                              hipStream_t stream) {
  const float* z  = (const float*)d_in[0];
  const float* AW = (const float*)d_in[1];
  const float* h  = (const float*)d_in[2];
  float* out = (float*)d_out;
  unsigned short* AWp = (unsigned short*)d_ws;                     // 512 KB packed bf16
  float* Adiag = (float*)((char*)d_ws + DZV * DZV * sizeof(unsigned short)); // 2 KB

  pack_b<<<128, 256, 0, stream>>>(AW, AWp, Adiag);
  plrnn_step<<<65536 / BM, 512, 0, stream>>>(z, h, AWp, Adiag, out);
}

// Round 2
// 318.860 us; speedup vs baseline: 1.0135x; 1.0135x over previous
//
#include <hip/hip_runtime.h>
#include <hip/hip_bf16.h>

// PLRNN step: out = A*z + relu(z - rowmean(z)) @ W^T + h,  A=diag(AW), W=AW-diag
// Rewritten: out = (z_act @ AW^T) + [A*min(z,mu) + h]   (exact identity)
// Round 5: round 4 (BM=64, epilogue corr-recompute) with PLAIN stores.
// Round-4 lesson: nontemporal stores on partial-line scatter (4x64B segments
// per instr) defeat L2 write-merging -> 2.1x WRITE_SIZE + RMW fetch. Plain
// stores merge in L2 (round 3: WRITE == exact out size with same pattern).

#define DZV 512
#define BM 64
#define LDA 520   // LDS row stride (shorts): 1040 B, 16B-aligned, 2-way-free banks

typedef __attribute__((ext_vector_type(8))) short short8;  // 8 bf16 = 4 VGPRs
typedef __attribute__((ext_vector_type(4))) float f32x4;   // MFMA C/D frag

__device__ __forceinline__ unsigned short f2bf(float x) {
  __hip_bfloat16 b = __float2bfloat16(x);
  return __builtin_bit_cast(unsigned short, b);
}

// Prep: pack AW (fp32) into bf16 MFMA-B-fragment order + extract diagonal.
// Frag idx=(T*16+s)*64+L holds 8 bf16 = AW[T*16+(L&15)][s*32+(L>>4)*8 + j]:
// a wave's B-frag load (lane L reads idx base+L) is 1KB contiguous, L2-hot.
__global__ void pack_b(const float* __restrict__ AW, unsigned short* __restrict__ AWp,
                       float* __restrict__ Adiag) {
  int idx = blockIdx.x * 256 + threadIdx.x;     // 0..32767
  int L = idx & 63, s = (idx >> 6) & 15, T = idx >> 10;
  int n = T * 16 + (L & 15);
  int k = s * 32 + (L >> 4) * 8;
  const float4* src = (const float4*)(AW + n * DZV + k);
  float4 a = src[0], b = src[1];
  union { unsigned short u[8]; short8 v; } p;
  p.u[0] = f2bf(a.x); p.u[1] = f2bf(a.y); p.u[2] = f2bf(a.z); p.u[3] = f2bf(a.w);
  p.u[4] = f2bf(b.x); p.u[5] = f2bf(b.y); p.u[6] = f2bf(b.z); p.u[7] = f2bf(b.w);
  *(short8*)(AWp + idx * 8) = p.v;
  if (idx < DZV) Adiag[idx] = AW[idx * (DZV + 1)];
}

__global__ __launch_bounds__(512, 4) void plrnn_step(
    const float* __restrict__ z, const float* __restrict__ h,
    const unsigned short* __restrict__ AWp, const float* __restrict__ Adiag,
    float* __restrict__ out)
{
  __shared__ unsigned short sA[BM * LDA];  // z_act panel (bf16), 66.6 KB
  __shared__ float sMu[BM];                // per-row mean, 256 B

  const int t = threadIdx.x;
  const int row0 = blockIdx.x * BM;

  const int lane = t & 63;
  const int wave = t >> 6;           // 8 waves cover N=512
  const int lr   = lane & 15;
  const int quad = lane >> 4;
  const int nbase = wave * 64;

  // B frag base pointers (packed global, lane-contiguous 1KB per frag-load)
  const unsigned short* bb[4];
  #pragma unroll
  for (int nt = 0; nt < 4; ++nt)
    bb[nt] = AWp + (((wave * 4 + nt) * 16) * 64 + lane) * 8;

  // ---- Phase 1: two coalesced passes over z (32 rows each); mean -> sMu,
  //      relu(z-mu) -> sA. No corr array: recomputed in epilogue. ----
  {
    const int rr = t >> 4;         // 0..31, 16 threads per row (consecutive lanes)
    const int c = t & 15;
    #pragma unroll
    for (int p = 0; p < 2; ++p) {
      const int r = p * 32 + rr;
      const float4* zr = (const float4*)(z + (row0 + r) * DZV);
      float4 v[8];
      float s = 0.f;
      #pragma unroll
      for (int i = 0; i < 8; ++i) {
        v[i] = zr[c + i * 16];                   // coalesced 256B runs
        s += (v[i].x + v[i].y) + (v[i].z + v[i].w);
      }
      s += __shfl_xor(s, 1);
      s += __shfl_xor(s, 2);
      s += __shfl_xor(s, 4);
      s += __shfl_xor(s, 8);
      const float mu = s * (1.0f / 512.0f);
      if (c == 0) sMu[r] = mu;
      #pragma unroll
      for (int i = 0; i < 8; ++i) {
        const int c4 = c + i * 16;               // float4 column index
        union { unsigned short u[4]; ushort4 v4; } pa;
        pa.u[0] = f2bf(fmaxf(v[i].x - mu, 0.f));
        pa.u[1] = f2bf(fmaxf(v[i].y - mu, 0.f));
        pa.u[2] = f2bf(fmaxf(v[i].z - mu, 0.f));
        pa.u[3] = f2bf(fmaxf(v[i].w - mu, 0.f));
        *(ushort4*)&sA[r * LDA + c4 * 4] = pa.v4;
      }
    }
  }

  // Pre-barrier B prefetch for s=0: loads fly during the barrier drain.
  short8 bf[2][4];
  #pragma unroll
  for (int nt = 0; nt < 4; ++nt)
    bf[0][nt] = *(const short8*)(bb[nt]);

  __syncthreads();   // only barrier; K-loop below is barrier-free

  // ---- Phase 2: GEMM, 4M x 4N frags per wave (64x64 tile).
  //      B double-buffered (L2 latency); A single-buffered (LDS latency,
  //      hidden by 4 waves/SIMD + previous iter's MFMA drain). ----
  const unsigned short* abase = &sA[lr * LDA + quad * 8];

  f32x4 acc[4][4];
  #pragma unroll
  for (int mt = 0; mt < 4; ++mt)
    #pragma unroll
    for (int nt = 0; nt < 4; ++nt)
      acc[mt][nt] = (f32x4){0.f, 0.f, 0.f, 0.f};

  short8 af[4];
  #pragma unroll
  for (int s = 0; s < 16; ++s) {     // k = s*32
    const int cur = s & 1, nxt = cur ^ 1;
    #pragma unroll
    for (int mt = 0; mt < 4; ++mt)   // A frags for THIS step (ds_read_b128)
      af[mt] = *(const short8*)(abase + mt * 16 * LDA + s * 32);
    if (s < 15) {                    // prefetch B for s+1 (L2, dwordx4)
      #pragma unroll
      for (int nt = 0; nt < 4; ++nt)
        bf[nxt][nt] = *(const short8*)(bb[nt] + (s + 1) * 512);
    }
    #pragma unroll
    for (int nt = 0; nt < 4; ++nt)
      #pragma unroll
      for (int mt = 0; mt < 4; ++mt)
        acc[mt][nt] = __builtin_amdgcn_mfma_f32_16x16x32_bf16(af[mt], bf[cur][nt], acc[mt][nt], 0, 0, 0);
  }

  // ---- Epilogue: corr = A*min(z,mu)+h recomputed from z (L2/L3-hot re-read).
  //      nt innermost -> 4 adjacent 64B segments per row, back-to-back, so
  //      L2 merges full lines (plain stores; NT defeated merging in round 4).
  float Ad[4], hv[4];
  #pragma unroll
  for (int nt = 0; nt < 4; ++nt) {
    const int col = nbase + nt * 16 + lr;
    Ad[nt] = Adiag[col];             // L1-hot, 2KB shared
    hv[nt] = h[col];
  }
  #pragma unroll
  for (int mt = 0; mt < 4; ++mt) {
    #pragma unroll
    for (int r = 0; r < 4; ++r) {
      const int lm = mt * 16 + quad * 4 + r;   // C/D layout: row = quad*4 + reg
      const float mu = sMu[lm];                // LDS broadcast (uniform per quad)
      const float* zrow = z + (row0 + lm) * DZV + nbase + lr;
      float* orow = out + (row0 + lm) * DZV + nbase + lr;
      #pragma unroll
      for (int nt = 0; nt < 4; ++nt) {
        const float zv = zrow[nt * 16];
        const float corr = Ad[nt] * fminf(zv, mu) + hv[nt];
        orow[nt * 16] = acc[mt][nt][r] + corr;
      }
    }
  }
}

extern "C" void kernel_launch(void* const* d_in, const int* in_sizes, int n_in,
                              void* d_out, int out_size, void* d_ws, size_t ws_size,
                              hipStream_t stream) {
  const float* z  = (const float*)d_in[0];
  const float* AW = (const float*)d_in[1];
  const float* h  = (const float*)d_in[2];
  float* out = (float*)d_out;
  unsigned short* AWp = (unsigned short*)d_ws;                     // 512 KB packed bf16
  float* Adiag = (float*)((char*)d_ws + DZV * DZV * sizeof(unsigned short)); // 2 KB

  pack_b<<<128, 256, 0, stream>>>(AW, AWp, Adiag);
  plrnn_step<<<65536 / BM, 512, 0, stream>>>(z, h, AWp, Adiag, out);
}